// Round 2
// baseline (1873.505 us; speedup 1.0000x reference)
//
#include <hip/hip_runtime.h>

// ModConv2D — StyleGAN2 modulated conv, fp32 I/O (reference dtypes).
// B=16, H=W=64, CIN=COUT=256, 3x3 SAME.
//
// Math: w[b,t,ci,co] = kernel[t,ci,co] * (style[b,ci]+1)
//       scale[b,co]  = 1/sqrt(sum_{t,ci} w^2 + 1e-8)
//       y[b,h,w,co]  = scale[b,co] * sum_{t,ci} x[b,h+dh,w+dw,ci]*(style[b,ci]+1)*kernel[t,ci,co]
// scale factors out of the conv; (style+1) folds into the x patch at LDS-fill.

#define BN   16
#define HH   64
#define WW   64
#define CI   256
#define CO   256
#define TAPS 9
#define WT   8          // outputs per thread along w (weight-reuse factor)
#define XPITCH 12       // padded col pitch for xs (48 B -> helps LDS read merging)

// Kernel A: scale[b][co]. grid=B, block=1024 (tid = q*256+co, q splits ci).
__global__ __launch_bounds__(1024) void modscale_kernel(
    const float* __restrict__ kern,    // [9][CI][CO]
    const float* __restrict__ style,   // [B][CI]
    float* __restrict__ scale)         // [B][CO]
{
    const int b   = blockIdx.x;
    const int tid = threadIdx.x;
    const int co  = tid & 255;
    const int q   = tid >> 8;   // 0..3

    __shared__ float s_style[CI];
    __shared__ float s_part[1024];

    if (tid < CI) s_style[tid] = style[b * CI + tid] + 1.0f;
    __syncthreads();

    float acc = 0.f;
    for (int t = 0; t < TAPS; ++t) {
        const float* kp = kern + (size_t)t * CI * CO + co;
        #pragma unroll 4
        for (int ci = q * 64; ci < q * 64 + 64; ++ci) {
            float m = kp[ci * CO] * s_style[ci];   // coalesced across co
            acc += m * m;
        }
    }
    s_part[tid] = acc;
    __syncthreads();
    if (q == 0) {
        float s = s_part[co] + s_part[256 + co] + s_part[512 + co] + s_part[768 + co];
        scale[b * CO + co] = 1.0f / sqrtf(s + 1e-8f);
    }
}

// Kernel B: direct conv with 8-wide spatial register blocking.
// Block = (b, h, w0..w0+7) x all 256 co; thread = co (= ci during staging).
// Modulated x patch (3 rows x 10 cols x 256 ci) in LDS; each weight element
// read once per block serves 8 FMAs.
__global__ __launch_bounds__(256) void conv_kernel(
    const float* __restrict__ x,       // [B][H][W][CI]
    const float* __restrict__ kern,    // [9][CI][CO]
    const float* __restrict__ style,   // [B][CI]
    const float* __restrict__ scale,   // [B][CO]
    float* __restrict__ y)             // [B][H][W][CO]
{
    const int blk = blockIdx.x;        // b*512 + h*8 + wq
    const int b   = blk >> 9;
    const int h   = (blk >> 3) & 63;
    const int w0  = (blk & 7) * WT;
    const int tid = threadIdx.x;

    __shared__ float xs[3 * CI * XPITCH];   // 36864 B

    const float sm = style[b * CI + tid] + 1.0f;   // tid == ci while staging

    // Stage rows h-1..h+1, cols w0-1..w0+8 (10 cols), pre-modulated, zero-padded.
    #pragma unroll
    for (int p = 0; p < 30; ++p) {
        const int dh  = p / 10;         // 0..2
        const int col = p % 10;         // 0..9
        const int row = h + dh - 1;
        const int c   = w0 + col - 1;
        float v = 0.f;
        if (row >= 0 && row < HH && c >= 0 && c < WW)
            v = x[((size_t)((b * HH + row) * WW + c)) * CI + tid] * sm;  // coalesced over tid
        xs[(dh * CI + tid) * XPITCH + col] = v;
    }
    __syncthreads();

    float acc[WT] = {0.f, 0.f, 0.f, 0.f, 0.f, 0.f, 0.f, 0.f};

    #pragma unroll
    for (int t = 0; t < TAPS; ++t) {
        const int dh = t / 3, c0 = t % 3;
        const float* wp = kern + (size_t)t * CI * CO + tid;   // column co=tid
        const float* xp = xs + dh * CI * XPITCH + c0;
        #pragma unroll 4
        for (int ci = 0; ci < CI; ++ci) {
            const float wv = wp[ci * CO];                      // coalesced, L2-hot
            #pragma unroll
            for (int r = 0; r < WT; ++r)
                acc[r] += xp[ci * XPITCH + r] * wv;            // LDS broadcast
        }
    }

    const float sc = scale[b * CO + tid];
    float* yp = y + ((size_t)(b * HH + h) * WW + w0) * CO + tid;
    #pragma unroll
    for (int r = 0; r < WT; ++r)
        yp[(size_t)r * CO] = acc[r] * sc;
}

extern "C" void kernel_launch(void* const* d_in, const int* in_sizes, int n_in,
                              void* d_out, int out_size, void* d_ws, size_t ws_size,
                              hipStream_t stream) {
    const float* x     = (const float*)d_in[0];  // [16,64,64,256]
    const float* style = (const float*)d_in[1];  // [16,256]
    const float* kern  = (const float*)d_in[2];  // [3,3,256,256]
    float* out = (float*)d_out;                  // [16,64,64,256]

    float* scale = (float*)d_ws;                 // 16*256 floats = 16 KB scratch

    modscale_kernel<<<BN, 1024, 0, stream>>>(kern, style, scale);
    conv_kernel<<<BN * HH * (WW / WT), 256, 0, stream>>>(x, kern, style, scale, out);
}

// Round 4
// 311.048 us; speedup vs baseline: 6.0232x; 6.0232x over previous
//
#include <hip/hip_runtime.h>

// ModConv2D — StyleGAN2 modulated conv as one implicit GEMM with f16 MFMA.
// B=16, H=W=64, CIN=COUT=256, 3x3 SAME, fp32 I/O.
//
//   Y[p=(b,h,w)][co] = scale[b,co] * sum_{k=(t,ci)} A[p][k] * W[k][co]
//   A[p][k] = x[b, h+dh(t)-1, w+dw(t)-1, ci] * (style[b,ci]+1)   (0 outside)
//   W shared across batch; scale[b,co] = demodulation factor (epilogue).
//
// GEMM: M=65536, N=256, K=2304. 128x128 tiles, BK=32, 4 waves of 4x4
// mfma_f32_16x16x32_f16. A modulated+converted at staging; W pre-transposed
// to [co][k] f16 in workspace so both frags are contiguous ds_read_b128.

#define HH 64
#define WW 64
#define CI 256
#define CO 256
#define KTOT 2304          // 9*256
#define PITCH 40           // LDS row pitch in ushorts (32 data + 8 pad; 80 B)

typedef float    f32x4 __attribute__((ext_vector_type(4)));
typedef _Float16 f16x8 __attribute__((ext_vector_type(8)));
typedef __fp16   fp16x2 __attribute__((ext_vector_type(2)));

__device__ __forceinline__ unsigned pk2(float a, float b) {
    fp16x2 h = __builtin_amdgcn_cvt_pkrtz(a, b);
    return __builtin_bit_cast(unsigned, h);
}

// ---- Kernel A: demod scale[b][co] (fp32, full precision) ----
__global__ __launch_bounds__(1024) void modscale_kernel(
    const float* __restrict__ kern,    // [9][CI][CO]
    const float* __restrict__ style,   // [B][CI]
    float* __restrict__ scale)         // [B][CO]
{
    const int b   = blockIdx.x;
    const int tid = threadIdx.x;
    const int co  = tid & 255;
    const int q   = tid >> 8;

    __shared__ float s_style[CI];
    __shared__ float s_part[1024];

    if (tid < CI) s_style[tid] = style[b * CI + tid] + 1.0f;
    __syncthreads();

    float acc = 0.f;
    for (int t = 0; t < 9; ++t) {
        const float* kp = kern + (size_t)t * CI * CO + co;
        #pragma unroll 4
        for (int ci = q * 64; ci < q * 64 + 64; ++ci) {
            float m = kp[ci * CO] * s_style[ci];
            acc += m * m;
        }
    }
    s_part[tid] = acc;
    __syncthreads();
    if (q == 0) {
        float s = s_part[co] + s_part[256 + co] + s_part[512 + co] + s_part[768 + co];
        scale[b * CO + co] = 1.0f / sqrtf(s + 1e-8f);
    }
}

// ---- Kernel B: transpose + f16-convert weights: Wt[co][k] ----
__global__ __launch_bounds__(256) void prep_wt(const float* __restrict__ kern,
                                               ushort* __restrict__ Wt) {
    __shared__ ushort tile[64][65];
    const int kt = blockIdx.x >> 2;        // 0..35
    const int ct = blockIdx.x & 3;         // 0..3
    const int k0 = kt * 64, c0 = ct * 64;
    const int tid = threadIdx.x;
    const int r = tid >> 2, q = tid & 3;   // r:0..63 q:0..3

    const float* src = kern + (size_t)(k0 + r) * CO + c0 + q * 16;
    #pragma unroll
    for (int j = 0; j < 16; ++j) {
        _Float16 h = (_Float16)src[j];
        tile[q * 16 + j][r] = __builtin_bit_cast(unsigned short, h);
    }
    __syncthreads();
    ushort* dst = Wt + (size_t)(c0 + r) * KTOT + k0 + q * 16;
    #pragma unroll
    for (int j = 0; j < 16; ++j) dst[j] = tile[r][q * 16 + j];
}

// ---- Kernel C: implicit-GEMM conv ----
__global__ __launch_bounds__(256) void gemm_conv(
    const float* __restrict__ x,        // [B][H][W][CI] fp32
    const ushort* __restrict__ Wt,      // [CO][KTOT] f16
    const float* __restrict__ style,    // [B][CI]
    const float* __restrict__ scale,    // [B][CO]
    float* __restrict__ y)              // [B][H][W][CO] fp32
{
    __shared__ __align__(16) ushort sA[128 * PITCH];
    __shared__ __align__(16) ushort sB[128 * PITCH];
    __shared__ __align__(16) float s_style[CI];

    const int tid  = threadIdx.x;
    const int lane = tid & 63;
    const int wave = tid >> 6;

    const int mtile = blockIdx.x >> 1;
    const int n0    = (blockIdx.x & 1) * 128;
    const int p0    = mtile * 128;            // 128 consecutive (b,h,w)
    const int b     = p0 >> 12;               // 4096 positions per image

    s_style[tid] = style[b * CI + tid] + 1.0f;

    // staging mapping: thread -> (row rr, 16-elem half)
    const int rr   = tid >> 1;                // 0..127
    const int half = tid & 1;
    const int ph   = ((p0 + rr) >> 6) & 63;
    const int pw   = (p0 + rr) & 63;

    const ushort* wt_row = Wt + (size_t)(n0 + rr) * KTOT + half * 16;

    f32x4 acc[4][4] = {};

    f32x4 a0, a1, a2, a3;
    uint4 b0v, b1v;
    int cur_ci0 = 0;

    auto load_iter = [&](int kk) {
        const int t   = kk >> 3;              // tap 0..8
        const int ci0 = (kk & 7) << 5;        // ci slice base
        cur_ci0 = ci0;
        const int dh  = t / 3 - 1;
        const int dw  = t - (t / 3) * 3 - 1;
        const int row = ph + dh, cw = pw + dw;
        const bool valid = ((unsigned)row < 64u) && ((unsigned)cw < 64u);
        if (valid) {
            const float* xp = x + (size_t)((b * HH + row) * WW + cw) * CI + ci0 + half * 16;
            a0 = *(const f32x4*)(xp);
            a1 = *(const f32x4*)(xp + 4);
            a2 = *(const f32x4*)(xp + 8);
            a3 = *(const f32x4*)(xp + 12);
        } else {
            a0 = (f32x4){0.f, 0.f, 0.f, 0.f};
            a1 = a0; a2 = a0; a3 = a0;
        }
        const ushort* bp = wt_row + kk * 32;
        b0v = *(const uint4*)(bp);
        b1v = *(const uint4*)(bp + 8);
    };

    auto store_iter = [&]() {
        const float* st = s_style + cur_ci0 + half * 16;
        f32x4 s0 = *(const f32x4*)(st);
        f32x4 s1 = *(const f32x4*)(st + 4);
        f32x4 s2 = *(const f32x4*)(st + 8);
        f32x4 s3 = *(const f32x4*)(st + 12);
        f32x4 m0 = a0 * s0, m1 = a1 * s1, m2 = a2 * s2, m3 = a3 * s3;
        uint4 u0, u1;
        u0.x = pk2(m0.x, m0.y); u0.y = pk2(m0.z, m0.w);
        u0.z = pk2(m1.x, m1.y); u0.w = pk2(m1.z, m1.w);
        u1.x = pk2(m2.x, m2.y); u1.y = pk2(m2.z, m2.w);
        u1.z = pk2(m3.x, m3.y); u1.w = pk2(m3.z, m3.w);
        ushort* pa = sA + rr * PITCH + half * 16;
        *(uint4*)(pa)     = u0;
        *(uint4*)(pa + 8) = u1;
        ushort* pb = sB + rr * PITCH + half * 16;
        *(uint4*)(pb)     = b0v;
        *(uint4*)(pb + 8) = b1v;
    };

    const int wm = (wave & 1) * 64;
    const int wn = (wave >> 1) * 64;
    const int fr = lane & 15;
    const int fq = lane >> 4;

    load_iter(0);
    for (int kk = 0; kk < 72; ++kk) {
        __syncthreads();                      // prev frag reads done
        store_iter();
        __syncthreads();                      // tiles visible
        if (kk < 71) load_iter(kk + 1);       // prefetch overlaps MFMA below
        f16x8 af[4], bf[4];
        #pragma unroll
        for (int i = 0; i < 4; ++i)
            af[i] = *(const f16x8*)(sA + (wm + i * 16 + fr) * PITCH + fq * 8);
        #pragma unroll
        for (int j = 0; j < 4; ++j)
            bf[j] = *(const f16x8*)(sB + (wn + j * 16 + fr) * PITCH + fq * 8);
        #pragma unroll
        for (int i = 0; i < 4; ++i) {
            #pragma unroll
            for (int j = 0; j < 4; ++j)
                acc[i][j] = __builtin_amdgcn_mfma_f32_16x16x32_f16(af[i], bf[j], acc[i][j], 0, 0, 0);
        }
    }

    // epilogue: D[m][co]: col = lane&15, row = (lane>>4)*4 + reg
    float sc[4];
    #pragma unroll
    for (int j = 0; j < 4; ++j)
        sc[j] = scale[b * CO + n0 + wn + j * 16 + fr];
    #pragma unroll
    for (int i = 0; i < 4; ++i) {
        const int m_base = p0 + wm + i * 16 + fq * 4;
        #pragma unroll
        for (int j = 0; j < 4; ++j) {
            float* yp = y + (size_t)m_base * CO + n0 + wn + j * 16 + fr;
            #pragma unroll
            for (int r = 0; r < 4; ++r)
                yp[(size_t)r * CO] = acc[i][j][r] * sc[j];
        }
    }
}

extern "C" void kernel_launch(void* const* d_in, const int* in_sizes, int n_in,
                              void* d_out, int out_size, void* d_ws, size_t ws_size,
                              hipStream_t stream) {
    const float* x     = (const float*)d_in[0];  // [16,64,64,256]
    const float* style = (const float*)d_in[1];  // [16,256]
    const float* kern  = (const float*)d_in[2];  // [3,3,256,256]
    float* out = (float*)d_out;                  // [16,64,64,256]

    float*  scale = (float*)d_ws;                         // 16*256 fp32 = 16 KB
    ushort* Wt    = (ushort*)((char*)d_ws + 16384);       // [256][2304] f16 = 1.18 MB

    modscale_kernel<<<16, 1024, 0, stream>>>(kern, style, scale);
    prep_wt<<<144, 256, 0, stream>>>(kern, Wt);
    gemm_conv<<<512 * 2, 256, 0, stream>>>(x, Wt, style, scale, out);
}

// Round 5
// 243.732 us; speedup vs baseline: 7.6868x; 1.2762x over previous
//
#include <hip/hip_runtime.h>

// ModConv2D — StyleGAN2 modulated conv as implicit GEMM, f16 MFMA.
// B=16, H=W=64, CIN=COUT=256, 3x3 SAME, fp32 I/O.
//
// Y[p][co] = rsqrt(sum w^2 + 1e-8)[b,co] * sum_k A[p][k] W[k][co],
// A = im2col(x) * (style+1) folded at staging, W batch-shared.
//
// R5 structure: K-loop is ci-slice-major (8 slices of 32), tap-minor (9).
// Per slice, a 4x66x32 modulated f16 x-window is staged ONCE in LDS and all
// 9 taps read shifted windows of it -> x fetched ~1x (+halo) instead of 9x.
// Weights staged 3 taps (96 k) at a time; barriers every 48 wave-MFMAs.

#define HH 64
#define WW 64
#define CI 256
#define CO 256
#define KTOT 2304
#define CIPITCH 40       // ushorts per (row,col): 32 ci + 8 pad (80 B -> <=2-way banks)
#define XCOLS 66
#define BPITCH 100       // ushorts per co row in bs: 96 k + 4 pad (200 B)

typedef float    f32x4 __attribute__((ext_vector_type(4)));
typedef _Float16 f16x8 __attribute__((ext_vector_type(8)));
typedef __fp16   fp16x2 __attribute__((ext_vector_type(2)));

__device__ __forceinline__ unsigned pk2(float a, float b) {
    fp16x2 h = __builtin_amdgcn_cvt_pkrtz(a, b);
    return __builtin_bit_cast(unsigned, h);
}

// ---- demod partial sums: scale2[b][co] += sum_ci (k*(s+1))^2 for one tap ----
__global__ __launch_bounds__(256) void modscale_part(
    const float* __restrict__ kern,    // [9][CI][CO]
    const float* __restrict__ style,   // [B][CI]
    float* __restrict__ scale2)        // [B][CO], pre-zeroed
{
    const int b = blockIdx.x / 9;
    const int t = blockIdx.x - b * 9;
    const int tid = threadIdx.x;
    __shared__ float st[CI];
    st[tid] = style[b * CI + tid] + 1.0f;
    __syncthreads();
    float acc = 0.f;
    const float* kp = kern + (size_t)t * CI * CO + tid;
    #pragma unroll 8
    for (int ci = 0; ci < CI; ++ci) {
        float m = kp[ci * CO] * st[ci];
        acc += m * m;
    }
    atomicAdd(&scale2[b * CO + tid], acc);
}

// ---- transpose + f16-convert weights: Wt[co][k] ----
__global__ __launch_bounds__(256) void prep_wt(const float* __restrict__ kern,
                                               ushort* __restrict__ Wt) {
    __shared__ ushort tile[64][65];
    const int kt = blockIdx.x >> 2;
    const int ct = blockIdx.x & 3;
    const int k0 = kt * 64, c0 = ct * 64;
    const int tid = threadIdx.x;
    const int r = tid >> 2, q = tid & 3;

    const float* src = kern + (size_t)(k0 + r) * CO + c0 + q * 16;
    #pragma unroll
    for (int j = 0; j < 16; ++j) {
        _Float16 h = (_Float16)src[j];
        tile[q * 16 + j][r] = __builtin_bit_cast(unsigned short, h);
    }
    __syncthreads();
    ushort* dst = Wt + (size_t)(c0 + r) * KTOT + k0 + q * 16;
    #pragma unroll
    for (int j = 0; j < 16; ++j) dst[j] = tile[r][q * 16 + j];
}

// ---- implicit-GEMM conv ----
__global__ __launch_bounds__(256) void gemm_conv(
    const float* __restrict__ x,        // [B][H][W][CI] fp32
    const ushort* __restrict__ Wt,      // [CO][KTOT] f16
    const float* __restrict__ style,    // [B][CI]
    const float* __restrict__ scale2,   // [B][CO] sum-of-squares
    float* __restrict__ y)              // [B][H][W][CO] fp32
{
    __shared__ __align__(16) ushort xs[4 * XCOLS * CIPITCH];  // 21120 B
    __shared__ __align__(16) ushort bs[128 * BPITCH];         // 25600 B
    __shared__ float s_style[CI];

    const int tid  = threadIdx.x;
    const int lane = tid & 63;
    const int wave = tid >> 6;

    const int mtile = blockIdx.x >> 1;
    const int n0    = (blockIdx.x & 1) * 128;
    const int p0    = mtile * 128;            // 2 image rows of one sample
    const int b     = p0 >> 12;
    const int h0    = (p0 >> 6) & 63;

    s_style[tid] = style[b * CI + tid] + 1.0f;

    const int wm = (wave & 1) * 64;
    const int wn = (wave >> 1) * 64;
    const int fr = lane & 15;
    const int fq = lane >> 4;
    const int xlane = fr * CIPITCH + fq * 8;   // per-lane A-frag offset

    f32x4 acc[4][4] = {};

    for (int c = 0; c < 8; ++c) {
        __syncthreads();   // previous slice's xs/bs readers done (also style for c=0)

        // ---- stage xs: 4 rows x 66 cols x 32 ci, modulated, f16 ----
        #pragma unroll
        for (int p = 0; p < 9; ++p) {
            const int task = p * 256 + tid;
            if (task < 2112) {
                const int rowcol = task >> 3;        // 0..263
                const int chunk  = task & 7;         // 4 floats each
                const int row = rowcol / XCOLS;
                const int col = rowcol - row * XCOLS;
                const int rg = h0 - 1 + row;
                const int cg = col - 1;
                f32x4 v = {0.f, 0.f, 0.f, 0.f};
                if ((unsigned)rg < 64u && (unsigned)cg < 64u)
                    v = *(const f32x4*)(x + ((size_t)((b * HH + rg) * WW + cg)) * CI
                                          + c * 32 + chunk * 4);
                const f32x4 st = *(const f32x4*)(s_style + c * 32 + chunk * 4);
                const f32x4 m = v * st;
                uint2 u;
                u.x = pk2(m.x, m.y);
                u.y = pk2(m.z, m.w);
                *(uint2*)(xs + rowcol * CIPITCH + chunk * 4) = u;
            }
        }

        #pragma unroll
        for (int tr = 0; tr < 3; ++tr) {
            if (tr) __syncthreads();   // prev tr's bs readers done

            // ---- stage bs: 128 co x 3 taps x 32 k ----
            #pragma unroll
            for (int p = 0; p < 6; ++p) {
                const int task = p * 256 + tid;      // < 1536
                const int co = task / 12;
                const int r  = task - co * 12;
                const int tl = r >> 2;
                const int ch = r & 3;
                const uint4 v = *(const uint4*)(Wt + (size_t)(n0 + co) * KTOT
                                                + (tr * 3 + tl) * 256 + c * 32 + ch * 8);
                *(uint4*)(bs + co * BPITCH + tl * 32 + ch * 8) = v;
            }
            __syncthreads();           // xs (tr==0) + bs visible

            #pragma unroll
            for (int tl = 0; tl < 3; ++tl) {
                const int t  = tr * 3 + tl;
                const int dh = t / 3;                // 0..2
                const int dw = t - dh * 3;           // 0..2

                f16x8 af[4], bf[4];
                #pragma unroll
                for (int i = 0; i < 4; ++i) {
                    const int mb   = wm + i * 16;
                    const int mrow = (mb >> 6) + dh;
                    const int mcol = (mb & 63) + dw;
                    af[i] = *(const f16x8*)(xs + (mrow * XCOLS + mcol) * CIPITCH + xlane);
                }
                #pragma unroll
                for (int j = 0; j < 4; ++j)
                    bf[j] = *(const f16x8*)(bs + (wn + j * 16 + fr) * BPITCH
                                            + tl * 32 + fq * 8);
                #pragma unroll
                for (int i = 0; i < 4; ++i)
                    #pragma unroll
                    for (int j = 0; j < 4; ++j)
                        acc[i][j] = __builtin_amdgcn_mfma_f32_16x16x32_f16(
                            af[i], bf[j], acc[i][j], 0, 0, 0);
            }
        }
    }

    // ---- epilogue: demod scale + store. D: col=lane&15, row=(lane>>4)*4+reg ----
    float sc[4];
    #pragma unroll
    for (int j = 0; j < 4; ++j)
        sc[j] = __frsqrt_rn(scale2[b * CO + n0 + wn + j * 16 + fr] + 1e-8f);
    #pragma unroll
    for (int i = 0; i < 4; ++i) {
        const int m_base = p0 + wm + i * 16 + fq * 4;
        #pragma unroll
        for (int j = 0; j < 4; ++j) {
            float* yp = y + (size_t)m_base * CO + n0 + wn + j * 16 + fr;
            #pragma unroll
            for (int r = 0; r < 4; ++r)
                yp[(size_t)r * CO] = acc[i][j][r] * sc[j];
        }
    }
}

extern "C" void kernel_launch(void* const* d_in, const int* in_sizes, int n_in,
                              void* d_out, int out_size, void* d_ws, size_t ws_size,
                              hipStream_t stream) {
    const float* x     = (const float*)d_in[0];  // [16,64,64,256]
    const float* style = (const float*)d_in[1];  // [16,256]
    const float* kern  = (const float*)d_in[2];  // [3,3,256,256]
    float* out = (float*)d_out;                  // [16,64,64,256]

    float*  scale2 = (float*)d_ws;                        // 16*256 fp32 = 16 KB
    ushort* Wt     = (ushort*)((char*)d_ws + 16384);      // [256][2304] f16

    hipMemsetAsync(scale2, 0, 16 * CO * sizeof(float), stream);
    modscale_part<<<16 * 9, 256, 0, stream>>>(kern, style, scale2);
    prep_wt<<<144, 256, 0, stream>>>(kern, Wt);
    gemm_conv<<<512 * 2, 256, 0, stream>>>(x, Wt, style, scale2, out);
}